// Round 8
// baseline (669.498 us; speedup 1.0000x reference)
//
#include <hip/hip_runtime.h>
#include <math.h>

typedef __bf16 bf16_t;
typedef bf16_t bf16x8 __attribute__((ext_vector_type(8)));
typedef float  floatx4 __attribute__((ext_vector_type(4)));

constexpr int N_SEQ = 4096, BSZ = 4, CIN = 384, CDSSP = 64, CHID = 128, NBLK = 4;
constexpr int NTOK = BSZ * N_SEQ;                       // 16384
constexpr int TOK_PER_WAVE  = 32;
constexpr int MLP_BLOCKS  = NTOK / TOK_PER_WAVE;        // 512 single-wave blocks
constexpr int FILL_BLOCKS = 8192;                       // 32 KB each
constexpr size_t OUT_ELEMS = (size_t)BSZ * N_SEQ * N_SEQ;

// ================= d_ws layout (16-byte units; 1 unit = 8 bf16) =================
// B-image: per kg-chunk 1024 units = [hi: nt*64+lane (512u)] || [lo: 512u].
//   input seq: 26 chunks (kg 0..11 = W_in, 12..23 = W_init, 24..25 = W_dssp)
//   hidden:    32 chunks = (rb*2+which)*4 + kg,  which 0=W1 1=W2
// A-image: relu'd inputs pre-split hi/lo in per-wave frag order:
//   hi unit = A_HI + w*3328 + kg*128 + mt*64 + lane   (w=tokengroup, kg 0..25)
//   lo unit = same + A_UNITS
constexpr int U_BIN   = 0;
constexpr int U_HID   = 26624;             // 26*1024
constexpr int B_END_U = 59392;             // + 32*1024
constexpr int A_HI_U  = 59392;
constexpr int A_UNITS = 1703936;           // 512 * 3328
constexpr int A_LO_U  = A_HI_U + A_UNITS;
constexpr int WS_END_U = A_LO_U + A_UNITS; // 3467264 u = 55.5 MB
constexpr int BAND_OFF = WS_END_U * 4;     // float index for band arrays
constexpr int PREP_B_THREADS = 29696;      // 116 blocks
constexpr int PREP_A_THREADS = A_UNITS;    // 6656 blocks

__device__ __forceinline__ float softplus_f(float x) {
    return fmaxf(x, 0.f) + log1pf(expf(-fabsf(x)));
}
__device__ __forceinline__ unsigned short bf16_bits(bf16_t h) {
    union { bf16_t b; unsigned short u; } c; c.b = h; return c.u;
}
__device__ __forceinline__ bf16_t bits_bf16(unsigned int u) {
    union { unsigned short u; bf16_t b; } c; c.u = (unsigned short)u; return c.b;
}
__device__ __forceinline__ floatx4 mfma16(bf16x8 a, bf16x8 b, floatx4 c) {
    return __builtin_amdgcn_mfma_f32_16x16x32_bf16(a, b, c, 0, 0, 0);
}

// ---- prep: build B-image (split weights) and A-image (relu+split inputs) ----
__global__ __launch_bounds__(256) void prep_kernel(
    const float* __restrict__ s, const float* __restrict__ s_init,
    const float* __restrict__ dssp,
    const float* __restrict__ Win, const float* __restrict__ Winit,
    const float* __restrict__ Wd,  const float* __restrict__ W1,
    const float* __restrict__ W2,  bf16_t* __restrict__ wsb)
{
    const int g = (int)blockIdx.x * 256 + (int)threadIdx.x;
    if (g < PREP_B_THREADS) {
        // ---- B-image: thread -> (chunk c, r = nt*64+lane); writes hi & lo unit ----
        const int c = g >> 9, r = g & 511;
        const int nt = r >> 6, lane = r & 63, col = lane & 15, q = lane >> 4;
        const int j = nt * 16 + col;
        const float* W; int C, kgl, cu;
        if (c < 12)      { W = Win;   C = CIN;   kgl = c;      cu = c; }
        else if (c < 24) { W = Winit; C = CIN;   kgl = c - 12; cu = c; }
        else if (c < 26) { W = Wd;    C = CDSSP; kgl = c - 24; cu = c; }
        else {
            const int hc = c - 26, m = hc >> 2;
            W = (m & 1) ? W2 : W1;
            W += (size_t)(m >> 1) * CHID * CHID;
            C = CHID; kgl = hc & 3; cu = c;
        }
        const float* sp = W + (size_t)j * C + (kgl * 4 + q) * 8;
        const float4 a = *(const float4*)sp;
        const float4 b = *(const float4*)(sp + 4);
        const float xs[8] = { a.x, a.y, a.z, a.w, b.x, b.y, b.z, b.w };
        bf16x8 vh, vl;
        #pragma unroll
        for (int i = 0; i < 8; ++i) {
            const float x = xs[i];
            const bf16_t h = (bf16_t)x;
            vh[i] = h; vl[i] = (bf16_t)(x - (float)h);
        }
        *(bf16x8*)(wsb + ((size_t)cu * 1024 + r) * 8)       = vh;
        *(bf16x8*)(wsb + ((size_t)cu * 1024 + 512 + r) * 8) = vl;
    } else {
        // ---- A-image: thread -> one (w, kg, mt, lane) unit; relu + split ----
        const int t2 = g - PREP_B_THREADS;               // 0 .. A_UNITS-1
        const int w  = t2 / 3328;
        const int r  = t2 - w * 3328;
        const int kg = r >> 7, r2 = r & 127;
        const int mt = r2 >> 6, lane = r2 & 63, col = lane & 15, q = lane >> 4;
        const int token = w * 32 + mt * 16 + col;
        const float* src; int C, kgl;
        if (kg < 12)      { src = s;      C = CIN;   kgl = kg; }
        else if (kg < 24) { src = s_init; C = CIN;   kgl = kg - 12; }
        else              { src = dssp;   C = CDSSP; kgl = kg - 24; }
        const float* sp = src + (size_t)token * C + kgl * 32 + q * 8;
        const float4 a = *(const float4*)sp;
        const float4 b = *(const float4*)(sp + 4);
        const float xs[8] = { a.x, a.y, a.z, a.w, b.x, b.y, b.z, b.w };
        bf16x8 vh, vl;
        #pragma unroll
        for (int i = 0; i < 8; ++i) {
            const float x = fmaxf(xs[i], 0.f);
            const bf16_t h = (bf16_t)x;
            vh[i] = h; vl[i] = (bf16_t)(x - (float)h);
        }
        *(bf16x8*)(wsb + ((size_t)A_HI_U + t2) * 8) = vh;
        *(bf16x8*)(wsb + ((size_t)A_LO_U + t2) * 8) = vl;
    }
}

// ---- B-frag register set ----
struct BF { bf16x8 h[8]; bf16x8 l[8]; };

__device__ __forceinline__ void loadB(const bf16_t* __restrict__ img, int kg, int lane, BF& B) {
    const bf16_t* cb = img + (size_t)(kg * 1024 + lane) * 8;
    #pragma unroll
    for (int nt = 0; nt < 8; ++nt) {
        B.h[nt] = *(const bf16x8*)(cb + (size_t)(nt * 64) * 8);
        B.l[nt] = *(const bf16x8*)(cb + (size_t)(512 + nt * 64) * 8);
    }
}

// term-major: 16 independent MFMAs between dependent uses; per-acc order hh,lh,hl
__device__ __forceinline__ void mfma_step(const bf16x8 (&ahi)[2], const bf16x8 (&alo)[2],
                                          const BF& B, floatx4 (&ac)[2][8]) {
    #pragma unroll
    for (int nt = 0; nt < 8; ++nt)
        #pragma unroll
        for (int mt = 0; mt < 2; ++mt)
            ac[mt][nt] = mfma16(ahi[mt], B.h[nt], ac[mt][nt]);
    #pragma unroll
    for (int nt = 0; nt < 8; ++nt)
        #pragma unroll
        for (int mt = 0; mt < 2; ++mt)
            ac[mt][nt] = mfma16(alo[mt], B.h[nt], ac[mt][nt]);
    #pragma unroll
    for (int nt = 0; nt < 8; ++nt)
        #pragma unroll
        for (int mt = 0; mt < 2; ++mt)
            ac[mt][nt] = mfma16(ahi[mt], B.l[nt], ac[mt][nt]);
}

// A-frags from the wave-private Act plane (packed hi|lo per k)
__device__ __forceinline__ void ldsA(const uint32_t (*A)[132], int kg, int col, int q,
                                     bf16x8 (&ahi)[2], bf16x8 (&alo)[2]) {
    #pragma unroll
    for (int mt = 0; mt < 2; ++mt) {
        const uint32_t* p = &A[mt * 16 + col][kg * 32 + q * 8];
        const uint4 u0 = *(const uint4*)p;
        const uint4 u1 = *(const uint4*)(p + 4);
        const uint32_t uu[8] = { u0.x, u0.y, u0.z, u0.w, u1.x, u1.y, u1.z, u1.w };
        union { uint32_t u[4]; bf16x8 v; } ch, cl;
        #pragma unroll
        for (int i = 0; i < 4; ++i) {
            ch.u[i] = (uu[2*i] & 0xffffu) | (uu[2*i+1] << 16);
            cl.u[i] = (uu[2*i] >> 16) | (uu[2*i+1] & 0xffff0000u);
        }
        ahi[mt] = ch.v; alo[mt] = cl.v;
    }
}

// hidden matmul (K=128), rolled kg loop, B double-buffered
__device__ __forceinline__ void hidden_pass(const uint32_t (*A)[132],
    const bf16_t* __restrict__ img, int lane, int col, int q, floatx4 (&ac)[2][8])
{
    BF B[2];
    loadB(img, 0, lane, B[0]);
    #pragma unroll 1
    for (int kg = 0; kg < 4; ++kg) {
        if (kg < 3) loadB(img, kg + 1, lane, B[(kg + 1) & 1]);
        bf16x8 ahi[2], alo[2];
        ldsA(A, kg, col, q, ahi, alo);
        mfma_step(ahi, alo, B[kg & 1], ac);
    }
}

// ---- fused MLP (blocks 0..511) + streaming zero-fill (blocks 512..8703) ----
__global__ __launch_bounds__(64) void mlp_fill_kernel(
    const float* __restrict__ b_in, const float* __restrict__ b_init,
    const float* __restrict__ b_dssp,
    const float* __restrict__ b1, const float* __restrict__ b2,
    const float* __restrict__ W_out, const float* __restrict__ b_out,
    const float* __restrict__ W_mult, const float* __restrict__ b_mult,
    const bf16_t* __restrict__ wsb, float* __restrict__ band,
    float* __restrict__ out)
{
    __shared__ uint32_t A[32][132];                 // 16.9 KB, wave-private act plane

    if (blockIdx.x >= MLP_BLOCKS) {
        const int f = (int)blockIdx.x - MLP_BLOCKS;
        floatx4* dst = (floatx4*)out + (size_t)f * 2048;   // 32 KB per block
        const floatx4 z = { 0.f, 0.f, 0.f, 0.f };
        #pragma unroll 1
        for (int i = (int)threadIdx.x; i < 2048; i += 64)
            __builtin_nontemporal_store(z, dst + i);
        return;
    }

    const int lane = (int)threadIdx.x;              // 0..63
    const int col  = lane & 15;
    const int q    = lane >> 4;
    const int w    = (int)blockIdx.x;               // token group
    const int t0w  = w * TOK_PER_WAVE;

    // h accumulators (C-frag layout): hacc[mt][nt] -> token mt*16+q*4+r, ch nt*16+col
    floatx4 hacc[2][8];
    #pragma unroll
    for (int nt = 0; nt < 8; ++nt) {
        const int j = nt * 16 + col;
        const float b = b_in[j] + b_init[j] + b_dssp[j];
        floatx4 v = { b, b, b, b };
        hacc[0][nt] = v; hacc[1][nt] = v;
    }

    // ---- input layer: one rolled loop, A+B both from coalesced global images ----
    {
        const bf16_t* ab = wsb + ((size_t)A_HI_U + (size_t)w * 3328 + lane) * 8;
        auto loadA = [&](int kg, bf16x8 (&ahi)[2], bf16x8 (&alo)[2]) {
            const bf16_t* p = ab + (size_t)(kg * 128) * 8;
            #pragma unroll
            for (int mt = 0; mt < 2; ++mt) {
                ahi[mt] = *(const bf16x8*)(p + (size_t)(mt * 64) * 8);
                alo[mt] = *(const bf16x8*)(p + ((size_t)A_UNITS + mt * 64) * 8);
            }
        };
        BF B[2];
        bf16x8 AH[2][2], AL[2][2];
        loadA(0, AH[0], AL[0]);
        loadB(wsb, 0, lane, B[0]);
        #pragma unroll 1
        for (int kg = 0; kg < 26; ++kg) {
            const int cur = kg & 1, nxt = cur ^ 1;
            if (kg + 1 < 26) {
                loadA(kg + 1, AH[nxt], AL[nxt]);
                loadB(wsb, kg + 1, lane, B[nxt]);
            }
            mfma_step(AH[cur], AL[cur], B[cur], hacc);
        }
    }

    // C-layout -> packed relu act plane
    auto exchange = [&](floatx4 (&ac)[2][8]) {
        #pragma unroll
        for (int mt = 0; mt < 2; ++mt)
        #pragma unroll
        for (int nt = 0; nt < 8; ++nt)
        #pragma unroll
        for (int r = 0; r < 4; ++r) {
            const float x = fmaxf(ac[mt][nt][r], 0.f);
            const bf16_t h = (bf16_t)x;
            const bf16_t l = (bf16_t)(x - (float)h);
            A[mt * 16 + q * 4 + r][nt * 16 + col] =
                (uint32_t)bf16_bits(h) | ((uint32_t)bf16_bits(l) << 16);
        }
        __syncthreads();   // 1-wave barrier: orders DS write->read
    };

    #pragma unroll 1
    for (int rb = 0; rb < NBLK; ++rb) {
        exchange(hacc);                               // A = relu(h)
        floatx4 vacc[2][8];
        #pragma unroll
        for (int nt = 0; nt < 8; ++nt) {
            const float b = b1[rb * CHID + nt * 16 + col];
            floatx4 v = { b, b, b, b };
            vacc[0][nt] = v; vacc[1][nt] = v;
        }
        hidden_pass(A, wsb + (size_t)(U_HID + (rb * 2 + 0) * 4096) * 8, lane, col, q, vacc);

        exchange(vacc);                               // A = relu(v)
        #pragma unroll
        for (int nt = 0; nt < 8; ++nt) {
            const float b = b2[rb * CHID + nt * 16 + col];
            #pragma unroll
            for (int mt = 0; mt < 2; ++mt) {
                floatx4 tt = hacc[mt][nt];
                tt[0] += b; tt[1] += b; tt[2] += b; tt[3] += b;
                hacc[mt][nt] = tt;
            }
        }
        hidden_pass(A, wsb + (size_t)(U_HID + (rb * 2 + 1) * 4096) * 8, lane, col, q, hacc);
    }
    exchange(hacc);                                   // A = relu(h_final)

    // ---- head: 7 fp32 dots/token; lanes 0-31 do o=0..3, lanes 32-63 do o=4,5,6 ----
    const int t    = lane & 31;
    const int half = lane >> 5;
    float d0v, d1v, d2v, d3v;
    const float *w0, *w1, *w2, *w3;
    if (half == 0) {
        w0 = W_out;          w1 = W_out + CHID; w2 = W_out + 2*CHID; w3 = W_out + 3*CHID;
        d0v = b_out[0]; d1v = b_out[1]; d2v = b_out[2]; d3v = b_out[3];
    } else {
        w0 = W_out + 4*CHID; w1 = W_mult;       w2 = W_mult + CHID;  w3 = W_out;
        d0v = b_out[4]; d1v = b_mult[0]; d2v = b_mult[1]; d3v = 0.f;
    }
    #pragma unroll 1
    for (int k = 0; k < CHID; ++k) {
        const uint32_t pk = A[t][k];
        const float x = (float)bits_bf16(pk & 0xffffu) + (float)bits_bf16(pk >> 16);
        d0v = fmaf(x, w0[k], d0v);
        d1v = fmaf(x, w1[k], d1v);
        d2v = fmaf(x, w2[k], d2v);
        d3v = fmaf(x, w3[k], d3v);
    }
    const float av = __shfl(d1v, 32 + t);
    const float bv = __shfl(d2v, 32 + t);
    const int g = t0w + t;
    if (half == 0) {
        band[g]            = softplus_f(d0v) * softplus_f(av) + softplus_f(bv);
        band[NTOK + g]     = d1v;   // c1
        band[2*NTOK + g]   = d2v;   // c2
        band[3*NTOK + g]   = d3v;   // c3
    } else {
        band[4*NTOK + g]   = d0v;   // c4
    }
}

// ---- patch the three diagonals (each cell fully overwritten; no RMW) ----
__global__ __launch_bounds__(256) void band_patch(
    const float* __restrict__ band, const float* __restrict__ p_sm,
    float* __restrict__ out)
{
    const int g = (int)blockIdx.x * 256 + (int)threadIdx.x;   // 0..16383
    const int b = g >> 12;
    const int i = g & (N_SEQ - 1);
    const float sm = *p_sm;
    const size_t rowbase = (size_t)b * N_SEQ * N_SEQ + (size_t)i * N_SEQ;
    out[rowbase + i] = sm * band[g];
    if (i >= 1) out[rowbase + i - 1] = sm * (band[NTOK + g] + band[3*NTOK + g - 1]);
    if (i >= 2) out[rowbase + i - 2] = sm * (band[2*NTOK + g] + band[4*NTOK + g - 2]);
}

extern "C" void kernel_launch(void* const* d_in, const int* in_sizes, int n_in,
                              void* d_out, int out_size, void* d_ws, size_t ws_size,
                              hipStream_t stream)
{
    const float* s      = (const float*)d_in[0];
    const float* s_init = (const float*)d_in[1];
    const float* dssp   = (const float*)d_in[2];
    const float* W_in   = (const float*)d_in[3];
    const float* b_in   = (const float*)d_in[4];
    const float* W_init = (const float*)d_in[5];
    const float* b_initp= (const float*)d_in[6];
    const float* W_dssp = (const float*)d_in[7];
    const float* b_dsspp= (const float*)d_in[8];
    const float* W1     = (const float*)d_in[9];
    const float* b1     = (const float*)d_in[10];
    const float* W2     = (const float*)d_in[11];
    const float* b2     = (const float*)d_in[12];
    const float* W_out  = (const float*)d_in[13];
    const float* b_out  = (const float*)d_in[14];
    const float* W_mult = (const float*)d_in[15];
    const float* b_mult = (const float*)d_in[16];
    const float* sm     = (const float*)d_in[17];
    bf16_t* wsb  = (bf16_t*)d_ws;
    float*  band = (float*)d_ws + BAND_OFF;
    float*  out  = (float*)d_out;

    const int prep_blocks = (PREP_B_THREADS + PREP_A_THREADS) / 256;   // 6772
    prep_kernel<<<prep_blocks, 256, 0, stream>>>(
        s, s_init, dssp, W_in, W_init, W_dssp, W1, W2, wsb);

    mlp_fill_kernel<<<MLP_BLOCKS + FILL_BLOCKS, 64, 0, stream>>>(
        b_in, b_initp, b_dsspp, b1, b2,
        W_out, b_out, W_mult, b_mult, (const bf16_t*)wsb, band, out);

    band_patch<<<NTOK / 256, 256, 0, stream>>>(band, sm, out);
}